// Round 1
// baseline (4781.321 us; speedup 1.0000x reference)
//
#include <hip/hip_runtime.h>
#include <stdint.h>

// ---------------- problem constants ----------------
#define BB   64
#define TSTEPS 256
#define VV   128
#define HHH  1024
#define G4   4096
#define KB0  36      // (128+1024)/32 k-blocks, layer 0
#define KB1  64      // (1024+1024)/32 k-blocks, layer 1

// workspace layout (bytes)
#define WPK0_OFF 0ull
#define WPK1_OFF 9437184ull
#define A0_OFF   26214400ull
#define A1_OFF   63963136ull
#define BIAS_OFF 131072000ull
#define CNT_OFF  131104768ull
// total needed: 131,137,536 B

typedef __attribute__((ext_vector_type(8))) short bf16x8;
typedef __attribute__((ext_vector_type(4))) float f32x4;

// round-to-nearest-even f32 -> bf16 (raw bits)
__device__ __forceinline__ unsigned short f2bf(float x) {
  unsigned int u = __float_as_uint(x);
  u = (u + 0x7FFFu + ((u >> 16) & 1u)) >> 16;
  return (unsigned short)u;
}

// position shuffle inside a 32-k block so each lane's 8 fragment elements
// (k in {4g..4g+3} U {16+4g..16+4g+3}, g = lane>>4) are 16B-contiguous.
__device__ __forceinline__ int kpos(int k) {
  return (((k & 15) >> 2) << 3) + (((k >> 4) & 1) << 2) + (k & 3);
}

__device__ __forceinline__ float sigm(float z) {
  return 1.0f / (1.0f + __expf(-z));
}

__device__ __forceinline__ void wait_ge(unsigned int* p, unsigned int v) {
  // relaxed poll (no L2-invalidate per iteration), single acquire at the end
  while (__hip_atomic_load(p, __ATOMIC_RELAXED, __HIP_MEMORY_SCOPE_AGENT) < v)
    __builtin_amdgcn_s_sleep(1);
  (void)__hip_atomic_load(p, __ATOMIC_ACQUIRE, __HIP_MEMORY_SCOPE_AGENT);
}

// ---------------- pre-kernels ----------------
__global__ void k_init(const float* __restrict__ bih0, const float* __restrict__ bhh0,
                       const float* __restrict__ bih1, const float* __restrict__ bhh1,
                       float* __restrict__ bias, unsigned int* __restrict__ cnt) {
  int i = blockIdx.x * 256 + threadIdx.x;   // 8192 threads
  cnt[i] = 0u;
  if (i < 4096) {
    bias[i]        = bih0[i] + bhh0[i];
    bias[4096 + i] = bih1[i] + bhh1[i];
  }
}

// pack [Wih | Whh] (4096 x K) -> fragment-native bf16
__global__ void k_packW(const float* __restrict__ Wih, const float* __restrict__ Whh,
                        const int Kih, const int KB, unsigned short* __restrict__ dst) {
  const int K = KB << 5;
  const int total = K << 12;                 // 4096*K
  int i = blockIdx.x * 256 + threadIdx.x;
  if (i >= total) return;
  int n = i / K, k = i - n * K;
  float w = (k < Kih) ? Wih[n * Kih + k] : Whh[n * 1024 + (k - Kih)];
  int gt = n >> 10, hcol = n & 1023;
  int wgi = hcol >> 3, j = hcol & 7;
  int nt = gt >> 1;
  int l15 = ((gt & 1) << 3) | j;             // ntile0: i|f cols, ntile1: g|o cols
  int kb = k >> 5;
  size_t idx = ((size_t)((wgi * 2 + nt) * KB + kb) << 9) + (l15 << 5) + kpos(k & 31);
  dst[idx] = f2bf(w);
}

// pack x (B,T,V) into A0(t) k=0..127 region for all t
__global__ void k_packX(const float* __restrict__ x, unsigned short* __restrict__ a0) {
  int i = blockIdx.x * 256 + threadIdx.x;    // 2,097,152 threads
  int v = i & 127, t = (i >> 7) & 255, b = i >> 15;
  a0[(size_t)t * 73728 + (size_t)(((v >> 5) << 6) + b) * 32 + kpos(v & 31)] = f2bf(x[i]);
}

// initial h: h[0] -> A0(0) k=128+hc ; h[1] -> A1(0) k=1024+hc
__global__ void k_packH(const float* __restrict__ h,
                        unsigned short* __restrict__ a0, unsigned short* __restrict__ a1) {
  int i = blockIdx.x * 256 + threadIdx.x;    // 131072 threads
  int l = i >> 16, b = (i >> 10) & 63, hc = i & 1023;
  unsigned short v = f2bf(h[i]);
  if (l == 0) {
    int k = 128 + hc;
    a0[(size_t)(((k >> 5) << 6) + b) * 32 + kpos(k & 31)] = v;
  } else {
    int k = 1024 + hc;
    a1[(size_t)(((k >> 5) << 6) + b) * 32 + kpos(k & 31)] = v;
  }
}

// ---------------- main persistent kernel ----------------
template <int LAYER>
__device__ __forceinline__ void run_layer(
    const int wg, const int tid,
    const float* __restrict__ c_in, float* __restrict__ out,
    const unsigned short* __restrict__ W,
    unsigned short* __restrict__ a0, unsigned short* __restrict__ a1,
    const float* __restrict__ bias, unsigned int* __restrict__ cnt,
    float (*red)[64][33]) {
  constexpr int KB = LAYER ? KB1 : KB0;
  constexpr int KBW = KB / 4;                 // k-blocks per wave (16 / 9)
  constexpr int AELEM = KB * 2048;            // elements per t-buffer

  const int lane = tid & 63, wv = tid >> 6;
  const int l15 = lane & 15, lg = lane >> 4;
  const int aoff = l15 * 32 + lg * 8;

  const unsigned short* Ard = LAYER ? a1 : a0;
  const unsigned short* Wt = W + (size_t)(wg * 2) * KB * 512 + aoff;

  unsigned int* cnt0 = cnt;
  unsigned int* cnt1 = cnt + 4096;

  // gate-math assignment: thread -> (batch row gb, h-col pair hc0, hc0+1)
  const int gb = tid >> 2, gj = (tid & 3) << 1;
  const int hc0 = wg * 8 + gj;
  float cc0 = c_in[LAYER * 65536 + gb * 1024 + hc0];
  float cc1 = c_in[LAYER * 65536 + gb * 1024 + hc0 + 1];
  float bg[4][2];
#pragma unroll
  for (int g = 0; g < 4; ++g) {
    bg[g][0] = bias[LAYER * 4096 + g * 1024 + hc0];
    bg[g][1] = bias[LAYER * 4096 + g * 1024 + hc0 + 1];
  }

  for (int t = 0; t < TSTEPS; ++t) {
    if (tid == 0) {
      if (LAYER == 0) {
        if (t) wait_ge(cnt0 + (t - 1) * 16, 128u);      // own lockstep: h0(t-1)
      } else {
        wait_ge(cnt0 + t * 16, 128u);                   // producer: h0(t)
        if (t) wait_ge(cnt1 + (t - 1) * 16, 128u);      // own lockstep: h1(t-1)
      }
    }
    __syncthreads();

    // ---- GEMM: z = A(t) @ Wslice^T, K split across 4 waves ----
    const unsigned short* Ak = Ard + (size_t)t * AELEM + (size_t)wv * KBW * 2048 + aoff;
    const unsigned short* Bk = Wt + (size_t)wv * KBW * 512;
    f32x4 acc[4][2];
#pragma unroll
    for (int mt = 0; mt < 4; ++mt) {
      acc[mt][0] = (f32x4){0.f, 0.f, 0.f, 0.f};
      acc[mt][1] = (f32x4){0.f, 0.f, 0.f, 0.f};
    }
#pragma unroll
    for (int kk = 0; kk < KBW; ++kk) {
      bf16x8 af0 = *(const bf16x8*)(Ak);
      bf16x8 af1 = *(const bf16x8*)(Ak + 512);
      bf16x8 af2 = *(const bf16x8*)(Ak + 1024);
      bf16x8 af3 = *(const bf16x8*)(Ak + 1536);
      bf16x8 bf0 = *(const bf16x8*)(Bk);
      bf16x8 bf1 = *(const bf16x8*)(Bk + KB * 512);
      acc[0][0] = __builtin_amdgcn_mfma_f32_16x16x32_bf16(af0, bf0, acc[0][0], 0, 0, 0);
      acc[1][0] = __builtin_amdgcn_mfma_f32_16x16x32_bf16(af1, bf0, acc[1][0], 0, 0, 0);
      acc[2][0] = __builtin_amdgcn_mfma_f32_16x16x32_bf16(af2, bf0, acc[2][0], 0, 0, 0);
      acc[3][0] = __builtin_amdgcn_mfma_f32_16x16x32_bf16(af3, bf0, acc[3][0], 0, 0, 0);
      acc[0][1] = __builtin_amdgcn_mfma_f32_16x16x32_bf16(af0, bf1, acc[0][1], 0, 0, 0);
      acc[1][1] = __builtin_amdgcn_mfma_f32_16x16x32_bf16(af1, bf1, acc[1][1], 0, 0, 0);
      acc[2][1] = __builtin_amdgcn_mfma_f32_16x16x32_bf16(af2, bf1, acc[2][1], 0, 0, 0);
      acc[3][1] = __builtin_amdgcn_mfma_f32_16x16x32_bf16(af3, bf1, acc[3][1], 0, 0, 0);
      Ak += 2048;
      Bk += 512;
    }

    // ---- cross-wave K reduction via LDS ----
#pragma unroll
    for (int mt = 0; mt < 4; ++mt)
#pragma unroll
      for (int nt = 0; nt < 2; ++nt)
#pragma unroll
        for (int r = 0; r < 4; ++r)
          red[wv][mt * 16 + lg * 4 + r][nt * 16 + l15] = acc[mt][nt][r];
    __syncthreads();

    // ---- gate math (f32), c kept in registers across all steps ----
    float z[4][2];
#pragma unroll
    for (int g = 0; g < 4; ++g) { z[g][0] = bg[g][0]; z[g][1] = bg[g][1]; }
#pragma unroll
    for (int w = 0; w < 4; ++w)
#pragma unroll
      for (int g = 0; g < 4; ++g) {
        z[g][0] += red[w][gb][g * 8 + gj];
        z[g][1] += red[w][gb][g * 8 + gj + 1];
      }
    float i0 = sigm(z[0][0]), f0 = sigm(z[1][0]), g0 = tanhf(z[2][0]), o0 = sigm(z[3][0]);
    cc0 = f0 * cc0 + i0 * g0;
    float hv0 = o0 * tanhf(cc0);
    float i1 = sigm(z[0][1]), f1 = sigm(z[1][1]), g1 = tanhf(z[2][1]), o1 = sigm(z[3][1]);
    cc1 = f1 * cc1 + i1 * g1;
    float hv1 = o1 * tanhf(cc1);

    unsigned int hpk = ((unsigned int)f2bf(hv1) << 16) | (unsigned int)f2bf(hv0);

    if (LAYER == 0) {
      {  // h0(t) -> A1(t) first half (k = hc)
        int k = hc0;
        size_t idx = (size_t)t * 131072 + (size_t)(((k >> 5) << 6) + gb) * 32 + kpos(k & 31);
        *(unsigned int*)(a1 + idx) = hpk;
      }
      if (t < TSTEPS - 1) {  // h0(t) -> A0(t+1) (k = 128+hc)
        int k = 128 + hc0;
        size_t idx = (size_t)(t + 1) * 73728 + (size_t)(((k >> 5) << 6) + gb) * 32 + kpos(k & 31);
        *(unsigned int*)(a0 + idx) = hpk;
      }
    } else {
      // outs[b][t][hc] in f32
      *(float2*)(out + ((size_t)gb * 256 + t) * 1024 + hc0) = make_float2(hv0, hv1);
      if (t < TSTEPS - 1) {  // h1(t) -> A1(t+1) second half (k = 1024+hc)
        int k = 1024 + hc0;
        size_t idx = (size_t)(t + 1) * 131072 + (size_t)(((k >> 5) << 6) + gb) * 32 + kpos(k & 31);
        *(unsigned int*)(a1 + idx) = hpk;
      }
    }
    if (t == TSTEPS - 1) {  // final h_f / c_f in f32
      size_t base = 16777216ull + (size_t)LAYER * 65536 + (size_t)gb * 1024 + hc0;
      out[base] = hv0;
      out[base + 1] = hv1;
      out[base + 131072] = cc0;
      out[base + 131072 + 1] = cc1;
    }

    __syncthreads();  // drains all threads' stores (vmcnt0 before s_barrier)
    if (tid == 0)
      (void)__hip_atomic_fetch_add((LAYER ? cnt1 : cnt0) + t * 16, 1u,
                                   __ATOMIC_RELEASE, __HIP_MEMORY_SCOPE_AGENT);
  }
}

__global__ __launch_bounds__(256, 1) void lstm_main(
    const float* __restrict__ c_in, float* __restrict__ out,
    const unsigned short* __restrict__ wpk0, const unsigned short* __restrict__ wpk1,
    unsigned short* a0, unsigned short* a1,
    const float* __restrict__ bias, unsigned int* cnt) {
  __shared__ float red[4][64][33];  // +1 pad: conflict-free reduce stores
  int bid = blockIdx.x, tid = threadIdx.x;
  if (bid < 128)
    run_layer<0>(bid, tid, c_in, out, wpk0, a0, a1, bias, cnt, red);
  else
    run_layer<1>(bid - 128, tid, c_in, out, wpk1, a0, a1, bias, cnt, red);
}

// ---------------- host ----------------
extern "C" void kernel_launch(void* const* d_in, const int* in_sizes, int n_in,
                              void* d_out, int out_size, void* d_ws, size_t ws_size,
                              hipStream_t stream) {
  const float* x    = (const float*)d_in[0];
  const float* h    = (const float*)d_in[1];
  const float* c    = (const float*)d_in[2];
  const float* Wih0 = (const float*)d_in[3];
  const float* Whh0 = (const float*)d_in[4];
  const float* bih0 = (const float*)d_in[5];
  const float* bhh0 = (const float*)d_in[6];
  const float* Wih1 = (const float*)d_in[7];
  const float* Whh1 = (const float*)d_in[8];
  const float* bih1 = (const float*)d_in[9];
  const float* bhh1 = (const float*)d_in[10];

  char* ws = (char*)d_ws;
  unsigned short* wpk0 = (unsigned short*)(ws + WPK0_OFF);
  unsigned short* wpk1 = (unsigned short*)(ws + WPK1_OFF);
  unsigned short* a0   = (unsigned short*)(ws + A0_OFF);
  unsigned short* a1   = (unsigned short*)(ws + A1_OFF);
  float* bias          = (float*)(ws + BIAS_OFF);
  unsigned int* cnt    = (unsigned int*)(ws + CNT_OFF);
  float* out = (float*)d_out;

  k_init<<<32, 256, 0, stream>>>(bih0, bhh0, bih1, bhh1, bias, cnt);
  k_packW<<<18432, 256, 0, stream>>>(Wih0, Whh0, 128, KB0, wpk0);
  k_packW<<<32768, 256, 0, stream>>>(Wih1, Whh1, 1024, KB1, wpk1);
  k_packX<<<8192, 256, 0, stream>>>(x, a0);
  k_packH<<<512, 256, 0, stream>>>(h, a0, a1);
  lstm_main<<<256, 256, 0, stream>>>(c, out, wpk0, wpk1, a0, a1, bias, cnt);
}